// Round 1
// baseline (816.049 us; speedup 1.0000x reference)
//
#include <hip/hip_runtime.h>

typedef unsigned short u16;
typedef unsigned int u32;

#define B_   4
#define S_   19950
#define C_   256
#define NH   8
#define NL   3
#define NP   4
#define DH   32
#define BS_  (B_*S_)          // 79800

#define TM 128
#define TN 64
#define TK 16
#define GRID_M ((BS_ + TM - 1)/TM)   // 624

__device__ __forceinline__ float bf2f(u16 u){ u32 x=((u32)u)<<16; float f; __builtin_memcpy(&f,&x,4); return f; }
__device__ __forceinline__ u16 f2bf(float f){ u32 x; __builtin_memcpy(&x,&f,4); x += 0x7fffu + ((x>>16)&1u); return (u16)(x>>16); }

// ---------------- GEMM 1: v = value @ W_val^T + b_val, stored bf16 permuted (b,h,s,dh) ----------------
__global__ __launch_bounds__(256) void k_vproj(const float* __restrict__ A,
    const float* __restrict__ W, const float* __restrict__ bias, u16* __restrict__ vout)
{
  __shared__ float As[TK][TM+4];
  __shared__ float Bs[TK][TN+4];
  const int tid = threadIdx.x;
  const int tx = tid & 15, ty = tid >> 4;
  const int r0 = blockIdx.x * TM;
  const int n0 = blockIdx.y * TN;
  const int ml = tid >> 2, kl = (tid & 3) << 2;
  float acc[8][4];
  #pragma unroll
  for (int i=0;i<8;++i){
    #pragma unroll
    for (int j=0;j<4;++j) acc[i][j]=0.f;
  }

  for (int k0=0;k0<C_;k0+=TK) {
    #pragma unroll
    for (int half=0; half<2; ++half) {
      const int m = ml + half*64;
      const int r = r0 + m;
      float4 a = make_float4(0.f,0.f,0.f,0.f);
      if (r < BS_) a = *(const float4*)(A + (size_t)r*C_ + k0 + kl);
      As[kl+0][m]=a.x; As[kl+1][m]=a.y; As[kl+2][m]=a.z; As[kl+3][m]=a.w;
    }
    {
      const int n = n0 + ml;
      float4 b = *(const float4*)(W + (size_t)n*C_ + k0 + kl);
      Bs[kl+0][ml]=b.x; Bs[kl+1][ml]=b.y; Bs[kl+2][ml]=b.z; Bs[kl+3][ml]=b.w;
    }
    __syncthreads();
    #pragma unroll
    for (int kk=0;kk<TK;++kk) {
      const float4 a0 = *(const float4*)&As[kk][ty*8];
      const float4 a1 = *(const float4*)&As[kk][ty*8+4];
      const float4 b0 = *(const float4*)&Bs[kk][tx*4];
      const float av[8]={a0.x,a0.y,a0.z,a0.w,a1.x,a1.y,a1.z,a1.w};
      const float bw[4]={b0.x,b0.y,b0.z,b0.w};
      #pragma unroll
      for (int i=0;i<8;++i){
        #pragma unroll
        for (int j=0;j<4;++j)
          acc[i][j] = fmaf(av[i], bw[j], acc[i][j]);
      }
    }
    __syncthreads();
  }

  const int nb = n0 + tx*4;
  const int h = nb >> 5, dh0 = nb & 31;
  const float b0v=bias[nb], b1v=bias[nb+1], b2v=bias[nb+2], b3v=bias[nb+3];
  #pragma unroll
  for (int i=0;i<8;++i) {
    const int r = r0 + ty*8 + i;
    if (r >= BS_) break;
    const int b = r / S_, s = r - b*S_;
    ushort4 pk = make_ushort4(f2bf(acc[i][0]+b0v), f2bf(acc[i][1]+b1v),
                              f2bf(acc[i][2]+b2v), f2bf(acc[i][3]+b3v));
    *(ushort4*)(vout + ((size_t)(b*NH+h)*S_ + s)*DH + dh0) = pk;
  }
}

// ---------------- GEMM 2: proj = query @ [W_off;W_attn]^T, epilogue: pack offsets + softmax attn ----------------
__global__ __launch_bounds__(256) void k_qproj(const float* __restrict__ A,
    const float* __restrict__ Woff, const float* __restrict__ boff,
    const float* __restrict__ Wattn, const float* __restrict__ battn,
    u16* __restrict__ soff, u16* __restrict__ sattn)
{
  __shared__ float As[TK][TM+4];
  __shared__ float Bs[TK][TN+4];
  const int tid = threadIdx.x;
  const int tx = tid & 15, ty = tid >> 4;
  const int r0 = blockIdx.x * TM;
  const int n0 = blockIdx.y * TN;
  const int ml = tid >> 2, kl = (tid & 3) << 2;
  float acc[8][4];
  #pragma unroll
  for (int i=0;i<8;++i){
    #pragma unroll
    for (int j=0;j<4;++j) acc[i][j]=0.f;
  }

  for (int k0=0;k0<C_;k0+=TK) {
    #pragma unroll
    for (int half=0; half<2; ++half) {
      const int m = ml + half*64;
      const int r = r0 + m;
      float4 a = make_float4(0.f,0.f,0.f,0.f);
      if (r < BS_) a = *(const float4*)(A + (size_t)r*C_ + k0 + kl);
      As[kl+0][m]=a.x; As[kl+1][m]=a.y; As[kl+2][m]=a.z; As[kl+3][m]=a.w;
    }
    {
      const int n = n0 + ml;
      float4 b = make_float4(0.f,0.f,0.f,0.f);
      if (n < 192)      b = *(const float4*)(Woff  + (size_t)n*C_ + k0 + kl);
      else if (n < 288) b = *(const float4*)(Wattn + (size_t)(n-192)*C_ + k0 + kl);
      Bs[kl+0][ml]=b.x; Bs[kl+1][ml]=b.y; Bs[kl+2][ml]=b.z; Bs[kl+3][ml]=b.w;
    }
    __syncthreads();
    #pragma unroll
    for (int kk=0;kk<TK;++kk) {
      const float4 a0 = *(const float4*)&As[kk][ty*8];
      const float4 a1 = *(const float4*)&As[kk][ty*8+4];
      const float4 b0 = *(const float4*)&Bs[kk][tx*4];
      const float av[8]={a0.x,a0.y,a0.z,a0.w,a1.x,a1.y,a1.z,a1.w};
      const float bw[4]={b0.x,b0.y,b0.z,b0.w};
      #pragma unroll
      for (int i=0;i<8;++i){
        #pragma unroll
        for (int j=0;j<4;++j)
          acc[i][j] = fmaf(av[i], bw[j], acc[i][j]);
      }
    }
    __syncthreads();
  }

  const int nb = n0 + tx*4;
  if (nb >= 288) return;
  const bool isoff = nb < 192;
  float bb[4];
  #pragma unroll
  for (int j=0;j<4;++j) bb[j] = isoff ? boff[nb+j] : battn[nb-192+j];

  #pragma unroll
  for (int i=0;i<8;++i) {
    const int r = r0 + ty*8 + i;
    if (r >= BS_) break;
    const float v0=acc[i][0]+bb[0], v1=acc[i][1]+bb[1], v2=acc[i][2]+bb[2], v3=acc[i][3]+bb[3];
    if (isoff) {
      // channels n = h*24 + l*8 + p*2 + xy  ->  point index pt = n/2 (two points per thread)
      ushort4 pk = make_ushort4(f2bf(v0), f2bf(v1), f2bf(v2), f2bf(v3));
      *(ushort4*)(soff + ((size_t)r*96 + (nb>>1))*2) = pk;
    } else {
      // attn logits, groups of 4 points per (h,l): softmax locally
      const float mx = fmaxf(fmaxf(v0,v1),fmaxf(v2,v3));
      const float e0=__expf(v0-mx), e1=__expf(v1-mx), e2=__expf(v2-mx), e3=__expf(v3-mx);
      const float inv = 1.f/(e0+e1+e2+e3);
      ushort4 pk = make_ushort4(f2bf(e0*inv), f2bf(e1*inv), f2bf(e2*inv), f2bf(e3*inv));
      *(ushort4*)(sattn + (size_t)r*96 + (nb-192)) = pk;
    }
  }
}

// ---------------- Sampling: per (b,h), 8 queries/block, lane = dh ----------------
#define QPB 8
#define NCHUNK ((S_ + QPB - 1)/QPB)   // 2494

__global__ __launch_bounds__(256) void k_sample(const u16* __restrict__ v,
    const u16* __restrict__ soff, const u16* __restrict__ sattn,
    const float* __restrict__ refp, u16* __restrict__ tmp)
{
  const int g = blockIdx.x;
  const int xcd = g & 7;
  const int inner = g >> 3;
  const int bh = xcd*4 + inner / NCHUNK;    // 4 (b,h)-slices per XCD for L2 locality
  const int chunk = inner % NCHUNK;
  const int b = bh >> 3, h = bh & 7;
  const int lane = threadIdx.x & 31;
  const int s = chunk*QPB + (threadIdx.x >> 5);
  if (s >= S_) return;
  const size_t r = (size_t)b*S_ + s;
  const float refx = refp[r*2+0], refy = refp[r*2+1];
  const u16* vb = v + (size_t)bh * S_ * DH;
  const u16* so = soff + (r*96 + h*12)*2;
  const u16* sa = sattn + r*96 + h*12;
  float acc = 0.f;
  const int WLs[3]={152,76,38}, HLs[3]={100,50,25}, STs[3]={0,15200,19000};
  #pragma unroll
  for (int idx=0; idx<12; ++idx) {
    const int l = idx>>2;
    const int Wl=WLs[l], Hl=HLs[l], st=STs[l];
    const float offx = bf2f(so[idx*2+0]);
    const float offy = bf2f(so[idx*2+1]);
    const float aw = bf2f(sa[idx]);
    // ix = ((ref + off/W)*2-1 +1)*0.5*W - 0.5 = ref*W + off - 0.5
    const float ix = refx*(float)Wl + offx - 0.5f;
    const float iy = refy*(float)Hl + offy - 0.5f;
    const float x0f = floorf(ix), y0f = floorf(iy);
    const float wx1 = ix-x0f, wy1 = iy-y0f;
    const float wx0 = 1.f-wx1, wy0 = 1.f-wy1;
    const int x0 = (int)x0f, y0 = (int)y0f;
    float sval = 0.f;
    #pragma unroll
    for (int dy=0; dy<2; ++dy) {
      const int yc = y0+dy;
      const bool vy = (yc>=0) && (yc<Hl);
      const int yi = min(max(yc,0),Hl-1);
      #pragma unroll
      for (int dx=0; dx<2; ++dx) {
        const int xc = x0+dx;
        const bool vx = (xc>=0) && (xc<Wl);
        const int xi = min(max(xc,0),Wl-1);
        const float w = (dx?wx1:wx0)*(dy?wy1:wy0);
        const float tap = bf2f(vb[(size_t)(st + yi*Wl + xi)*DH + lane]);
        sval += (vx&&vy) ? tap*w : 0.f;
      }
    }
    acc += aw * sval;
  }
  tmp[r*C_ + (size_t)h*DH + lane] = f2bf(acc);
}

// ---------------- GEMM 3: out = tmp(bf16) @ W_out^T + b_out (f32 out) ----------------
__global__ __launch_bounds__(256) void k_outproj(const u16* __restrict__ A,
    const float* __restrict__ W, const float* __restrict__ bias, float* __restrict__ outp)
{
  __shared__ float As[TK][TM+4];
  __shared__ float Bs[TK][TN+4];
  const int tid = threadIdx.x;
  const int tx = tid & 15, ty = tid >> 4;
  const int r0 = blockIdx.x * TM;
  const int n0 = blockIdx.y * TN;
  const int ml = tid >> 2, kl = (tid & 3) << 2;
  float acc[8][4];
  #pragma unroll
  for (int i=0;i<8;++i){
    #pragma unroll
    for (int j=0;j<4;++j) acc[i][j]=0.f;
  }

  for (int k0=0;k0<C_;k0+=TK) {
    #pragma unroll
    for (int half=0; half<2; ++half) {
      const int m = ml + half*64;
      const int r = r0 + m;
      ushort4 a = make_ushort4(0,0,0,0);
      if (r < BS_) a = *(const ushort4*)(A + (size_t)r*C_ + k0 + kl);
      As[kl+0][m]=bf2f(a.x); As[kl+1][m]=bf2f(a.y); As[kl+2][m]=bf2f(a.z); As[kl+3][m]=bf2f(a.w);
    }
    {
      const int n = n0 + ml;
      float4 b = *(const float4*)(W + (size_t)n*C_ + k0 + kl);
      Bs[kl+0][ml]=b.x; Bs[kl+1][ml]=b.y; Bs[kl+2][ml]=b.z; Bs[kl+3][ml]=b.w;
    }
    __syncthreads();
    #pragma unroll
    for (int kk=0;kk<TK;++kk) {
      const float4 a0 = *(const float4*)&As[kk][ty*8];
      const float4 a1 = *(const float4*)&As[kk][ty*8+4];
      const float4 b0 = *(const float4*)&Bs[kk][tx*4];
      const float av[8]={a0.x,a0.y,a0.z,a0.w,a1.x,a1.y,a1.z,a1.w};
      const float bw[4]={b0.x,b0.y,b0.z,b0.w};
      #pragma unroll
      for (int i=0;i<8;++i){
        #pragma unroll
        for (int j=0;j<4;++j)
          acc[i][j] = fmaf(av[i], bw[j], acc[i][j]);
      }
    }
    __syncthreads();
  }

  const int nb = n0 + tx*4;
  const float b0v=bias[nb], b1v=bias[nb+1], b2v=bias[nb+2], b3v=bias[nb+3];
  #pragma unroll
  for (int i=0;i<8;++i) {
    const int r = r0 + ty*8 + i;
    if (r >= BS_) break;
    float4 o = make_float4(acc[i][0]+b0v, acc[i][1]+b1v, acc[i][2]+b2v, acc[i][3]+b3v);
    *(float4*)(outp + (size_t)r*C_ + nb) = o;
  }
}

extern "C" void kernel_launch(void* const* d_in, const int* in_sizes, int n_in,
                              void* d_out, int out_size, void* d_ws, size_t ws_size,
                              hipStream_t stream) {
  (void)in_sizes; (void)n_in; (void)out_size; (void)ws_size;
  const float* query = (const float*)d_in[0];
  const float* value = (const float*)d_in[1];
  // d_in[2] spatial_shapes, d_in[3] level_start_index: compile-time constants
  const float* refp  = (const float*)d_in[4];
  const float* W_off = (const float*)d_in[5];
  const float* b_off = (const float*)d_in[6];
  const float* W_attn= (const float*)d_in[7];
  const float* b_attn= (const float*)d_in[8];
  const float* W_val = (const float*)d_in[9];
  const float* b_val = (const float*)d_in[10];
  const float* W_out = (const float*)d_in[11];
  const float* b_out = (const float*)d_in[12];
  float* out = (float*)d_out;

  char* ws = (char*)d_ws;
  constexpr size_t V_BYTES    = (size_t)BS_*C_*2;     // 40,857,600
  constexpr size_t SOFF_BYTES = (size_t)BS_*96*4;     // 30,643,200
  constexpr size_t SATTN_BYTES= (size_t)BS_*96*2;     // 15,321,600
  u16* v     = (u16*)(ws);
  u16* soff  = (u16*)(ws + V_BYTES);
  u16* sattn = (u16*)(ws + V_BYTES + SOFF_BYTES);
  u16* tmp   = (u16*)(ws + V_BYTES + SOFF_BYTES + SATTN_BYTES);

  dim3 blk(256);
  hipLaunchKernelGGL(k_vproj,   dim3(GRID_M,4), blk, 0, stream, value, W_val, b_val, v);
  hipLaunchKernelGGL(k_qproj,   dim3(GRID_M,5), blk, 0, stream, query, W_off, b_off, W_attn, b_attn, soff, sattn);
  hipLaunchKernelGGL(k_sample,  dim3(8*4*NCHUNK), blk, 0, stream, v, soff, sattn, refp, tmp);
  hipLaunchKernelGGL(k_outproj, dim3(GRID_M,4), blk, 0, stream, tmp, W_out, b_out, out);
}

// Round 2
// 434.838 us; speedup vs baseline: 1.8767x; 1.8767x over previous
//
#include <hip/hip_runtime.h>
#include <hip/hip_bf16.h>

typedef unsigned short u16;
typedef unsigned int u32;
typedef __attribute__((ext_vector_type(8))) short short8v;   // 8 bf16 MFMA frag
typedef __attribute__((ext_vector_type(4))) float f32x4;
typedef __attribute__((ext_vector_type(8))) unsigned short us8;
typedef __attribute__((ext_vector_type(4))) unsigned int uint4v;
typedef __attribute__((ext_vector_type(2))) unsigned int uint2v;

#define B_   4
#define S_   19950
#define C_   256
#define NH   8
#define DH   32
#define BS_  (B_*S_)          // 79800

#define BM 128
#define BN 128
#define BK 64
#define GRID_M ((BS_ + BM - 1)/BM)   // 624

__device__ __forceinline__ float bf2f(u16 u){ u32 x=((u32)u)<<16; float f; __builtin_memcpy(&f,&x,4); return f; }
// RNE f32->bf16 (bit trick, proven round 0)
__device__ __forceinline__ u16 f2bf(float f){ u32 x; __builtin_memcpy(&x,&f,4); x += 0x7fffu + ((x>>16)&1u); return (u16)(x>>16); }
// HW packed convert (RNE), 2 f32 -> u32 of 2 bf16
__device__ __forceinline__ u32 cvtpk(float a, float b){ u32 r; asm("v_cvt_pk_bf16_f32 %0, %1, %2" : "=v"(r) : "v"(a), "v"(b)); return r; }

// ================= MFMA GEMM: C[M,N] = A[M,256] * W[N,256]^T =================
// MODE 0: A=value f32, W=W_val      -> v bf16 permuted (b,h,s,dh)      (out0)
// MODE 1: A=query f32, W=Woff/Wattn -> soff bf16 (out0) + softmaxed sattn bf16 (out1)
// MODE 2: A=tmp bf16,  W=W_out      -> out f32                         (out0)
template<int MODE>
__global__ __launch_bounds__(256) void k_gemm(
    const void* __restrict__ Aany, const float* __restrict__ Wmain,
    const float* __restrict__ Wattn, const float* __restrict__ bmain,
    const float* __restrict__ battn, void* __restrict__ out0, u16* __restrict__ out1)
{
  __shared__ u32 AsW[BM*32];   // 128 rows x 64 bf16 (32 u32), XOR-swizzled 16B chunks
  __shared__ u32 BsW[BN*32];
  const int tid = threadIdx.x;
  const int m0 = blockIdx.y * BM;
  const int n0 = blockIdx.x * BN;
  const int lane = tid & 63;
  const int wid  = tid >> 6;
  const int wm = wid >> 1, wn = wid & 1;
  const int ln15 = lane & 15, ln4 = lane >> 4;

  f32x4 acc[4][4];
  #pragma unroll
  for (int i=0;i<4;++i){
    #pragma unroll
    for (int j=0;j<4;++j) acc[i][j] = (f32x4){0.f,0.f,0.f,0.f};
  }

  for (int kt=0; kt<4; ++kt) {
    const int k0 = kt*64;
    // ---- stage A ----
    if (MODE==2) {
      const u16* A = (const u16*)Aany;
      #pragma unroll
      for (int i=0;i<4;++i){
        const int ct = tid + 256*i;          // 1024 chunks of 8 bf16 (16B)
        const int row = ct >> 3, c = ct & 7;
        const int gr = m0 + row;
        uint4v val = (uint4v){0,0,0,0};
        if (gr < BS_) val = *(const uint4v*)(A + (size_t)gr*C_ + k0 + c*8);
        *(uint4v*)&AsW[row*32 + ((c ^ (row&7))<<2)] = val;
      }
    } else {
      const float* A = (const float*)Aany;
      #pragma unroll
      for (int i=0;i<8;++i){
        const int ct = tid + 256*i;          // 2048 chunks of 4 f32 (16B)
        const int row = ct >> 4, c = ct & 15;
        const int gr = m0 + row;
        f32x4 vv = (f32x4){0.f,0.f,0.f,0.f};
        if (gr < BS_) vv = *(const f32x4*)(A + (size_t)gr*C_ + k0 + c*4);
        const u32 p0 = cvtpk(vv.x, vv.y), p1 = cvtpk(vv.z, vv.w);
        const int cc = c >> 1;
        uint2v pk; pk.x = p0; pk.y = p1;
        *(uint2v*)&AsW[row*32 + ((cc ^ (row&7))<<2) + (c&1)*2] = pk;
      }
    }
    // ---- stage B (weights, f32 source) ----
    {
      #pragma unroll
      for (int i=0;i<8;++i){
        const int ct = tid + 256*i;
        const int row = ct >> 4, c = ct & 15;
        const int n = n0 + row;
        f32x4 vv = (f32x4){0.f,0.f,0.f,0.f};
        if (MODE==1) {
          if (n < 192)      vv = *(const f32x4*)(Wmain + (size_t)n*C_ + k0 + c*4);
          else if (n < 288) vv = *(const f32x4*)(Wattn + (size_t)(n-192)*C_ + k0 + c*4);
        } else {
          vv = *(const f32x4*)(Wmain + (size_t)n*C_ + k0 + c*4);
        }
        const u32 p0 = cvtpk(vv.x, vv.y), p1 = cvtpk(vv.z, vv.w);
        const int cc = c >> 1;
        uint2v pk; pk.x = p0; pk.y = p1;
        *(uint2v*)&BsW[row*32 + ((cc ^ (row&7))<<2) + (c&1)*2] = pk;
      }
    }
    __syncthreads();
    // ---- compute: 2 k-sub of 32, 4x4 frags ----
    #pragma unroll
    for (int ks=0; ks<2; ++ks) {
      short8v af[4], bf[4];
      #pragma unroll
      for (int mi=0;mi<4;++mi){
        const int row = wm*64 + mi*16 + ln15;
        const int c = ks*4 + ln4;
        af[mi] = *(const short8v*)&AsW[row*32 + ((c ^ (row&7))<<2)];
      }
      #pragma unroll
      for (int ni=0;ni<4;++ni){
        const int row = wn*64 + ni*16 + ln15;
        const int c = ks*4 + ln4;
        bf[ni] = *(const short8v*)&BsW[row*32 + ((c ^ (row&7))<<2)];
      }
      #pragma unroll
      for (int mi=0;mi<4;++mi){
        #pragma unroll
        for (int ni=0;ni<4;++ni)
          acc[mi][ni] = __builtin_amdgcn_mfma_f32_16x16x32_bf16(af[mi], bf[ni], acc[mi][ni], 0, 0, 0);
      }
    }
    __syncthreads();
  }

  // ---- epilogue ----
  #pragma unroll
  for (int mi=0;mi<4;++mi){
    #pragma unroll
    for (int ni=0;ni<4;++ni){
      const int n = n0 + wn*64 + ni*16 + ln15;
      if (MODE==1 && n >= 288) continue;
      float bias;
      if (MODE==1) bias = (n < 192) ? bmain[n] : battn[n-192];
      else         bias = bmain[n];
      if (MODE==1 && n >= 192) {
        // softmax over 4 consecutive n-channels = 4-lane group
        #pragma unroll
        for (int j=0;j<4;++j){
          const int m = m0 + wm*64 + mi*16 + ln4*4 + j;
          const float vv = acc[mi][ni][j] + bias;
          float mx = vv;
          mx = fmaxf(mx, __shfl_xor(mx, 1));
          mx = fmaxf(mx, __shfl_xor(mx, 2));
          const float e = __expf(vv - mx);
          float ssum = e;
          ssum += __shfl_xor(ssum, 1);
          ssum += __shfl_xor(ssum, 2);
          if (m < BS_) out1[(size_t)m*96 + (n-192)] = f2bf(e/ssum);
        }
      } else if (MODE==1) {
        u16* soff = (u16*)out0;
        #pragma unroll
        for (int j=0;j<4;++j){
          const int m = m0 + wm*64 + mi*16 + ln4*4 + j;
          if (m < BS_) soff[(size_t)m*192 + n] = f2bf(acc[mi][ni][j] + bias);
        }
      } else if (MODE==0) {
        u16* vout = (u16*)out0;
        const int h = n >> 5, dh = n & 31;
        #pragma unroll
        for (int j=0;j<4;++j){
          const int m = m0 + wm*64 + mi*16 + ln4*4 + j;
          if (m < BS_) {
            const int bq = m / S_, s = m - bq*S_;
            vout[((size_t)(bq*NH+h)*S_ + s)*DH + dh] = f2bf(acc[mi][ni][j] + bias);
          }
        }
      } else {
        float* outp = (float*)out0;
        #pragma unroll
        for (int j=0;j<4;++j){
          const int m = m0 + wm*64 + mi*16 + ln4*4 + j;
          if (m < BS_) outp[(size_t)m*C_ + n] = acc[mi][ni][j] + bias;
        }
      }
    }
  }
}

// ================= Sampler v2: 4 channels/thread, (bh, s-half) XCD units =================
#define NCHH 312   // ceil(624/2) chunks of 32 queries per s-half

__global__ __launch_bounds__(256) void k_sample2(const u16* __restrict__ v,
    const u16* __restrict__ soff, const u16* __restrict__ sattn,
    const float* __restrict__ refp, u16* __restrict__ tmp)
{
  const int g = blockIdx.x;
  const int xcd = g & 7, inner = g >> 3;      // inner in [0, 2496)
  const int unit = inner / NCHH;              // 0..7 : (bh-slice, s-half)
  const int cidx = inner - unit*NCHH;
  const int bh = xcd*4 + (unit >> 1);
  const int chunk = (unit & 1)*NCHH + cidx;   // 0..623
  const int b = bh >> 3, h = bh & 7;
  const int dh0 = (threadIdx.x & 7) * 4;
  const int q = chunk*32 + (threadIdx.x >> 3);
  if (q >= S_) return;
  const size_t r = (size_t)b*S_ + q;
  const float refx = refp[r*2+0], refy = refp[r*2+1];
  const u16* vb = v + (size_t)bh * S_ * DH;

  const u16* sop = soff + r*192 + h*24;
  const u16* sap = sattn + r*96 + h*12;
  us8 so0 = *(const us8*)(sop);
  us8 so1 = *(const us8*)(sop + 8);
  us8 so2 = *(const us8*)(sop + 16);
  ushort4 sa0 = *(const ushort4*)(sap);
  ushort4 sa1 = *(const ushort4*)(sap + 4);
  ushort4 sa2 = *(const ushort4*)(sap + 8);
  u16 soarr[24]; u16 saarr[12];
  #pragma unroll
  for (int i=0;i<8;++i){ soarr[i]=so0[i]; soarr[8+i]=so1[i]; soarr[16+i]=so2[i]; }
  saarr[0]=sa0.x; saarr[1]=sa0.y; saarr[2]=sa0.z; saarr[3]=sa0.w;
  saarr[4]=sa1.x; saarr[5]=sa1.y; saarr[6]=sa1.z; saarr[7]=sa1.w;
  saarr[8]=sa2.x; saarr[9]=sa2.y; saarr[10]=sa2.z; saarr[11]=sa2.w;

  float acc0=0.f, acc1=0.f, acc2=0.f, acc3=0.f;
  const int WLs[3]={152,76,38}, HLs[3]={100,50,25}, STs[3]={0,15200,19000};
  #pragma unroll
  for (int idx=0; idx<12; ++idx) {
    const int l = idx>>2;
    const int Wl=WLs[l], Hl=HLs[l], st=STs[l];
    // ix = ref*W + off - 0.5 (normalizer algebra folded)
    const float ix = refx*(float)Wl + bf2f(soarr[2*idx+0]) - 0.5f;
    const float iy = refy*(float)Hl + bf2f(soarr[2*idx+1]) - 0.5f;
    const float aw = bf2f(saarr[idx]);
    const float x0f = floorf(ix), y0f = floorf(iy);
    const float wx1 = ix-x0f, wy1 = iy-y0f;
    const float wx0 = 1.f-wx1, wy0 = 1.f-wy1;
    const int x0 = (int)x0f, y0 = (int)y0f;
    #pragma unroll
    for (int dy=0; dy<2; ++dy) {
      const int yc = y0+dy;
      const bool vy = (yc>=0) && (yc<Hl);
      const int yi = min(max(yc,0),Hl-1);
      #pragma unroll
      for (int dx=0; dx<2; ++dx) {
        const int xc = x0+dx;
        const bool vx = (xc>=0) && (xc<Wl);
        const int xi = min(max(xc,0),Wl-1);
        float w = aw * (dx?wx1:wx0) * (dy?wy1:wy0);
        if (!(vx && vy)) w = 0.f;
        const ushort4 t = *(const ushort4*)(vb + (size_t)(st + yi*Wl + xi)*DH + dh0);
        acc0 = fmaf(w, bf2f(t.x), acc0);
        acc1 = fmaf(w, bf2f(t.y), acc1);
        acc2 = fmaf(w, bf2f(t.z), acc2);
        acc3 = fmaf(w, bf2f(t.w), acc3);
      }
    }
  }
  *(ushort4*)(tmp + r*C_ + (size_t)h*DH + dh0) =
      make_ushort4(f2bf(acc0), f2bf(acc1), f2bf(acc2), f2bf(acc3));
}

extern "C" void kernel_launch(void* const* d_in, const int* in_sizes, int n_in,
                              void* d_out, int out_size, void* d_ws, size_t ws_size,
                              hipStream_t stream) {
  (void)in_sizes; (void)n_in; (void)out_size; (void)ws_size;
  const float* query = (const float*)d_in[0];
  const float* value = (const float*)d_in[1];
  const float* refp  = (const float*)d_in[4];
  const float* W_off = (const float*)d_in[5];
  const float* b_off = (const float*)d_in[6];
  const float* W_attn= (const float*)d_in[7];
  const float* b_attn= (const float*)d_in[8];
  const float* W_val = (const float*)d_in[9];
  const float* b_val = (const float*)d_in[10];
  const float* W_out = (const float*)d_in[11];
  const float* b_out = (const float*)d_in[12];
  float* out = (float*)d_out;

  char* ws = (char*)d_ws;
  constexpr size_t V_BYTES    = (size_t)BS_*C_*2;     // 40.9 MB: v bf16 (b,h,s,dh)
  constexpr size_t SOFF_BYTES = (size_t)BS_*192*2;    // 30.6 MB
  constexpr size_t SATTN_BYTES= (size_t)BS_*96*2;     // 15.3 MB
  u16* v     = (u16*)(ws);
  u16* soff  = (u16*)(ws + V_BYTES);
  u16* sattn = (u16*)(ws + V_BYTES + SOFF_BYTES);
  u16* tmp   = (u16*)(ws + V_BYTES + SOFF_BYTES + SATTN_BYTES);

  dim3 blk(256);
  hipLaunchKernelGGL((k_gemm<0>), dim3(2, GRID_M), blk, 0, stream,
                     (const void*)value, W_val, (const float*)nullptr, b_val,
                     (const float*)nullptr, (void*)v, (u16*)nullptr);
  hipLaunchKernelGGL((k_gemm<1>), dim3(3, GRID_M), blk, 0, stream,
                     (const void*)query, W_off, W_attn, b_off, b_attn,
                     (void*)soff, sattn);
  hipLaunchKernelGGL(k_sample2, dim3(8*8*NCHH), blk, 0, stream, v, soff, sattn, refp, tmp);
  hipLaunchKernelGGL((k_gemm<2>), dim3(2, GRID_M), blk, 0, stream,
                     (const void*)tmp, W_out, (const float*)nullptr, b_out,
                     (const float*)nullptr, (void*)out, (u16*)nullptr);
}

// Round 4
// 318.168 us; speedup vs baseline: 2.5648x; 1.3667x over previous
//
#include <hip/hip_runtime.h>

typedef unsigned short u16;
typedef unsigned int u32;
typedef __attribute__((ext_vector_type(8))) short short8v;   // 8 bf16 MFMA frag
typedef __attribute__((ext_vector_type(4))) float f32x4;
typedef __attribute__((ext_vector_type(2))) float f32x2;
typedef __attribute__((ext_vector_type(4))) unsigned int uint4v;
typedef __attribute__((ext_vector_type(2))) unsigned int uint2v;
typedef __attribute__((ext_vector_type(8))) unsigned short us8;

#define B_   4
#define S_   19950
#define C_   256
#define NH   8
#define DH   32
#define BS_  (B_*S_)          // 79800

#define BM 128
#define BN 128
#define BK 64

__device__ __forceinline__ float bf2f(u16 u){ u32 x=((u32)u)<<16; float f; __builtin_memcpy(&f,&x,4); return f; }
__device__ __forceinline__ u16 f2bf(float f){ u32 x; __builtin_memcpy(&x,&f,4); x += 0x7fffu + ((x>>16)&1u); return (u16)(x>>16); }
__device__ __forceinline__ u32 cvtpk(float a, float b){ u32 r; asm("v_cvt_pk_bf16_f32 %0, %1, %2" : "=v"(r) : "v"(a), "v"(b)); return r; }
// packed fp32 fma: d = a*b + d (2 lanes)
__device__ __forceinline__ f32x2 pkfma(f32x2 a, f32x2 b, f32x2 d){
  asm("v_pk_fma_f32 %0, %1, %2, %0" : "+v"(d) : "v"(a), "v"(b)); return d;
}
// u32 holding 2 bf16 -> f32x2
__device__ __forceinline__ f32x2 unpk(u32 p){
  uint2v u; u.x = p<<16; u.y = p & 0xffff0000u; return __builtin_bit_cast(f32x2, u);
}

// ================= MFMA GEMM core: C[M,N] = A[M,256] * W[N,256]^T =================
// MODE 0: A=value f32, W=W_val      -> v bf16 permuted (b,h,s,dh)      (out0)
// MODE 1: A=query f32, W=Woff/Wattn -> soff bf16 (out0) + softmaxed sattn bf16 (out1)
// MODE 2: A=tmp bf16,  W=W_out      -> out f32                         (out0)
// A staged via async global_load_lds (f32 for MODE0/1, bf16 for MODE2): LDS dest is
// linear/wave-uniform, XOR swizzle applied by pre-swizzling the per-lane SOURCE address
// and applying the same XOR on the read side (both-sides rule). B (weights, L2-hot)
// staged through regs with cvt to bf16 + swizzled ds_write.
template<int MODE>
__device__ __forceinline__ void gemm_core(
    const void* __restrict__ Aany, const float* __restrict__ Wmain,
    const float* __restrict__ Wattn, const float* __restrict__ bmain,
    const float* __restrict__ battn, void* __restrict__ out0, u16* __restrict__ out1)
{
  constexpr int NX = (MODE==1) ? 3 : 2;
  __shared__ float Asf[(MODE==2) ? 4 : BM*BK];   // 32 KB f32 A-tile (16 chunks of 16B per row)
  __shared__ u16  Asb[(MODE==2) ? BM*BK : 4];    // 16 KB bf16 A-tile (8 chunks of 16B per row)
  __shared__ u32  Bs[BN*32];                     // 16 KB bf16 B-tile

  const int tid = threadIdx.x;
  const int g = blockIdx.x;
  const int x = (g>>3) % NX;
  const int y = ((g>>3)/NX)*8 + (g&7);   // XCD-paired: col-blocks of one A-panel are 8 apart -> same XCD
  const int m0 = y * BM;
  const int n0 = x * BN;
  const int lane = tid & 63;
  const int wid  = tid >> 6;
  const int wm = wid >> 1, wn = wid & 1;
  const int ln15 = lane & 15, ln4 = lane >> 4;

  f32x4 acc[4][4];
  #pragma unroll
  for (int i=0;i<4;++i){
    #pragma unroll
    for (int j=0;j<4;++j) acc[i][j] = (f32x4){0.f,0.f,0.f,0.f};
  }

  for (int kt=0; kt<4; ++kt) {
    const int k0 = kt*BK;
    // ---- B loads into regs (issued first; their wait leaves the A-DMA in flight) ----
    f32x4 bvv[8];
    #pragma unroll
    for (int i=0;i<8;++i){
      const int ct = tid + 256*i;
      const int row = ct >> 4, c = ct & 15;
      const int n = n0 + row;
      f32x4 vv = (f32x4){0.f,0.f,0.f,0.f};
      if constexpr (MODE==1) {
        if (n < 192)      vv = *(const f32x4*)(Wmain + (size_t)n*C_ + k0 + c*4);
        else if (n < 288) vv = *(const f32x4*)(Wattn + (size_t)(n-192)*C_ + k0 + c*4);
      } else {
        vv = *(const f32x4*)(Wmain + (size_t)n*C_ + k0 + c*4);
      }
      bvv[i] = vv;
    }
    // ---- A async DMA to LDS (linear dest, inverse-swizzled source) ----
    if constexpr (MODE==2) {
      const u16* Ab = (const u16*)Aany;
      #pragma unroll
      for (int i=0;i<4;++i){
        const int rl = wid*32 + i*8 + (lane>>3);
        const int rg = min(m0 + rl, BS_-1);
        const int c = lane & 7, cs = c ^ (rl & 7);
        const u16* src = Ab + (size_t)rg*C_ + k0 + cs*8;
        __builtin_amdgcn_global_load_lds(src, &Asb[(wid*32 + i*8)*64], 16, 0, 0);
      }
    } else {
      const float* Ab = (const float*)Aany;
      #pragma unroll
      for (int i=0;i<8;++i){
        const int rl = wid*32 + i*4 + (lane>>4);
        const int rg = min(m0 + rl, BS_-1);
        const int c = lane & 15, cs = c ^ (rl & 15);
        const float* src = Ab + (size_t)rg*C_ + k0 + cs*4;
        __builtin_amdgcn_global_load_lds(src, &Asf[(wid*32 + i*4)*64], 16, 0, 0);
      }
    }
    // ---- B cvt + swizzled LDS write ----
    #pragma unroll
    for (int i=0;i<8;++i){
      const int ct = tid + 256*i;
      const int row = ct >> 4, c = ct & 15;
      const u32 p0 = cvtpk(bvv[i].x, bvv[i].y), p1 = cvtpk(bvv[i].z, bvv[i].w);
      const int cc = c >> 1;
      uint2v pk; pk.x = p0; pk.y = p1;
      *(uint2v*)&Bs[row*32 + ((cc ^ (row&7))<<2) + (c&1)*2] = pk;
    }
    __syncthreads();   // drains A-DMA (vmcnt) + B writes (lgkmcnt)
    // ---- compute: 2 k-sub of 32, 4x4 frags ----
    #pragma unroll
    for (int ks=0; ks<2; ++ks) {
      short8v af[4], bfr[4];
      #pragma unroll
      for (int mi=0;mi<4;++mi){
        const int row = wm*64 + mi*16 + ln15;
        if constexpr (MODE==2) {
          const int c = ks*4 + ln4;
          af[mi] = *(const short8v*)&Asb[row*64 + ((c ^ (row&7))<<3)];
        } else {
          const int ch = ks*8 + ln4*2;
          const int c1 = ch ^ (row&15), c2 = (ch+1) ^ (row&15);
          const f32x4 lo = *(const f32x4*)&Asf[row*64 + c1*4];
          const f32x4 hi = *(const f32x4*)&Asf[row*64 + c2*4];
          uint4v uu;
          uu.x = cvtpk(lo.x, lo.y); uu.y = cvtpk(lo.z, lo.w);
          uu.z = cvtpk(hi.x, hi.y); uu.w = cvtpk(hi.z, hi.w);
          af[mi] = __builtin_bit_cast(short8v, uu);
        }
      }
      #pragma unroll
      for (int ni=0;ni<4;++ni){
        const int row = wn*64 + ni*16 + ln15;
        const int c = ks*4 + ln4;
        bfr[ni] = *(const short8v*)&Bs[row*32 + ((c ^ (row&7))<<2)];
      }
      #pragma unroll
      for (int mi=0;mi<4;++mi){
        #pragma unroll
        for (int ni=0;ni<4;++ni)
          acc[mi][ni] = __builtin_amdgcn_mfma_f32_16x16x32_bf16(af[mi], bfr[ni], acc[mi][ni], 0, 0, 0);
      }
    }
    __syncthreads();
  }

  // ---- epilogue (validated round 2) ----
  #pragma unroll
  for (int mi=0;mi<4;++mi){
    #pragma unroll
    for (int ni=0;ni<4;++ni){
      const int n = n0 + wn*64 + ni*16 + ln15;
      if (MODE==1 && n >= 288) continue;
      float bias;
      if constexpr (MODE==1) bias = (n < 192) ? bmain[n] : battn[n-192];
      else                   bias = bmain[n];
      if (MODE==1 && n >= 192) {
        #pragma unroll
        for (int j=0;j<4;++j){
          const int m = m0 + wm*64 + mi*16 + ln4*4 + j;
          const float vv = acc[mi][ni][j] + bias;
          float mx = vv;
          mx = fmaxf(mx, __shfl_xor(mx, 1));
          mx = fmaxf(mx, __shfl_xor(mx, 2));
          const float e = __expf(vv - mx);
          float ssum = e;
          ssum += __shfl_xor(ssum, 1);
          ssum += __shfl_xor(ssum, 2);
          if (m < BS_) out1[(size_t)m*96 + (n-192)] = f2bf(e/ssum);
        }
      } else if (MODE==1) {
        u16* soff = (u16*)out0;
        #pragma unroll
        for (int j=0;j<4;++j){
          const int m = m0 + wm*64 + mi*16 + ln4*4 + j;
          if (m < BS_) soff[(size_t)m*192 + n] = f2bf(acc[mi][ni][j] + bias);
        }
      } else if (MODE==0) {
        u16* vout = (u16*)out0;
        const int h = n >> 5, dh = n & 31;
        #pragma unroll
        for (int j=0;j<4;++j){
          const int m = m0 + wm*64 + mi*16 + ln4*4 + j;
          if (m < BS_) {
            const int bq = m / S_, s = m - bq*S_;
            vout[((size_t)(bq*NH+h)*S_ + s)*DH + dh] = f2bf(acc[mi][ni][j] + bias);
          }
        }
      } else {
        float* outp = (float*)out0;
        #pragma unroll
        for (int j=0;j<4;++j){
          const int m = m0 + wm*64 + mi*16 + ln4*4 + j;
          if (m < BS_) outp[(size_t)m*C_ + n] = acc[mi][ni][j] + bias;
        }
      }
    }
  }
}

// Plain (non-template) kernels -> host stubs always emitted.
__global__ __launch_bounds__(256) void k_gemm0(const void* __restrict__ A,
    const float* __restrict__ W, const float* __restrict__ b, void* __restrict__ o)
{ gemm_core<0>(A, W, nullptr, b, nullptr, o, nullptr); }

__global__ __launch_bounds__(256) void k_gemm1(const void* __restrict__ A,
    const float* __restrict__ Wm, const float* __restrict__ Wa,
    const float* __restrict__ bm, const float* __restrict__ ba,
    void* __restrict__ o0, u16* __restrict__ o1)
{ gemm_core<1>(A, Wm, Wa, bm, ba, o0, o1); }

__global__ __launch_bounds__(256) void k_gemm2(const void* __restrict__ A,
    const float* __restrict__ W, const float* __restrict__ b, void* __restrict__ o)
{ gemm_core<2>(A, W, nullptr, b, nullptr, o, nullptr); }

// ================= Sampler v3: 8 ch/thread, packed-fp32 tap blend =================
#define NCH 312   // ceil(19950/64) chunks of 64 queries

__global__ __launch_bounds__(256) void k_sample3(const u16* __restrict__ v,
    const u16* __restrict__ soff, const u16* __restrict__ sattn,
    const float* __restrict__ refp, u16* __restrict__ tmp)
{
  const int g = blockIdx.x;
  const int xcd = g & 7, inner = g >> 3;      // inner in [0, 4*NCH)
  const int unit = inner / NCH;               // 0..3
  const int cidx = inner - unit*NCH;
  const int bh = xcd*4 + unit;                // 4 (b,h)-slices per XCD for L2 locality
  const int b = bh >> 3, h = bh & 7;
  const int dh0 = (threadIdx.x & 3) * 8;
  const int q = cidx*64 + (threadIdx.x >> 2);
  if (q >= S_) return;
  const size_t r = (size_t)b*S_ + q;
  const float refx = refp[r*2+0], refy = refp[r*2+1];
  const u16* vb = v + (size_t)bh * S_ * DH;

  const u16* sop = soff + r*192 + h*24;
  const u16* sap = sattn + r*96 + h*12;
  us8 so0 = *(const us8*)(sop);
  us8 so1 = *(const us8*)(sop + 8);
  us8 so2 = *(const us8*)(sop + 16);
  ushort4 sa0 = *(const ushort4*)(sap);
  ushort4 sa1 = *(const ushort4*)(sap + 4);
  ushort4 sa2 = *(const ushort4*)(sap + 8);
  u16 soarr[24]; u16 saarr[12];
  #pragma unroll
  for (int i=0;i<8;++i){ soarr[i]=so0[i]; soarr[8+i]=so1[i]; soarr[16+i]=so2[i]; }
  saarr[0]=sa0.x; saarr[1]=sa0.y; saarr[2]=sa0.z; saarr[3]=sa0.w;
  saarr[4]=sa1.x; saarr[5]=sa1.y; saarr[6]=sa1.z; saarr[7]=sa1.w;
  saarr[8]=sa2.x; saarr[9]=sa2.y; saarr[10]=sa2.z; saarr[11]=sa2.w;

  f32x2 acc0 = (f32x2){0.f,0.f}, acc1 = acc0, acc2 = acc0, acc3 = acc0;
  const int WLs[3]={152,76,38}, HLs[3]={100,50,25}, STs[3]={0,15200,19000};
  #pragma unroll
  for (int l=0;l<3;++l) {
    const int Wl=WLs[l], Hl=HLs[l];
    const float rxl = refx*(float)Wl - 0.5f;   // ix = ref*W + off - 0.5 (normalizer folded)
    const float ryl = refy*(float)Hl - 0.5f;
    const u16* vbl = vb + (size_t)STs[l]*DH;
    #pragma unroll
    for (int p=0;p<4;++p) {
      const int idx = l*4 + p;
      const float ix = rxl + bf2f(soarr[2*idx+0]);
      const float iy = ryl + bf2f(soarr[2*idx+1]);
      const float aw = bf2f(saarr[idx]);
      const float x0f = floorf(ix), y0f = floorf(iy);
      const float wx1 = ix-x0f, wy1 = iy-y0f;
      const float wx0 = 1.f-wx1, wy0 = 1.f-wy1;
      const int x0 = (int)x0f, y0 = (int)y0f;
      #pragma unroll
      for (int dy=0; dy<2; ++dy) {
        const int yc = y0+dy;
        const bool vy = (yc>=0) && (yc<Hl);
        const int yi = min(max(yc,0),Hl-1);
        const float wyf = aw * (dy?wy1:wy0);
        #pragma unroll
        for (int dx=0; dx<2; ++dx) {
          const int xc = x0+dx;
          const bool vx = (xc>=0) && (xc<Wl);
          const int xi = min(max(xc,0),Wl-1);
          float w = wyf * (dx?wx1:wx0);
          if (!(vx && vy)) w = 0.f;
          f32x2 w2; w2.x = w; w2.y = w;
          const uint4v t = *(const uint4v*)(vbl + (size_t)(yi*Wl + xi)*DH + dh0);
          acc0 = pkfma(unpk(t.x), w2, acc0);
          acc1 = pkfma(unpk(t.y), w2, acc1);
          acc2 = pkfma(unpk(t.z), w2, acc2);
          acc3 = pkfma(unpk(t.w), w2, acc3);
        }
      }
    }
  }
  uint4v o;
  o.x = cvtpk(acc0.x, acc0.y); o.y = cvtpk(acc1.x, acc1.y);
  o.z = cvtpk(acc2.x, acc2.y); o.w = cvtpk(acc3.x, acc3.y);
  *(uint4v*)(tmp + r*C_ + (size_t)h*DH + dh0) = o;
}

extern "C" void kernel_launch(void* const* d_in, const int* in_sizes, int n_in,
                              void* d_out, int out_size, void* d_ws, size_t ws_size,
                              hipStream_t stream) {
  (void)in_sizes; (void)n_in; (void)out_size; (void)ws_size;
  const float* query = (const float*)d_in[0];
  const float* value = (const float*)d_in[1];
  const float* refp  = (const float*)d_in[4];
  const float* W_off = (const float*)d_in[5];
  const float* b_off = (const float*)d_in[6];
  const float* W_attn= (const float*)d_in[7];
  const float* b_attn= (const float*)d_in[8];
  const float* W_val = (const float*)d_in[9];
  const float* b_val = (const float*)d_in[10];
  const float* W_out = (const float*)d_in[11];
  const float* b_out = (const float*)d_in[12];
  float* out = (float*)d_out;

  char* ws = (char*)d_ws;
  constexpr size_t V_BYTES    = (size_t)BS_*C_*2;     // 40.9 MB: v bf16 (b,h,s,dh)
  constexpr size_t SOFF_BYTES = (size_t)BS_*192*2;    // 30.6 MB
  constexpr size_t SATTN_BYTES= (size_t)BS_*96*2;     // 15.3 MB
  u16* v     = (u16*)(ws);
  u16* soff  = (u16*)(ws + V_BYTES);
  u16* sattn = (u16*)(ws + V_BYTES + SOFF_BYTES);
  u16* tmp   = (u16*)(ws + V_BYTES + SOFF_BYTES + SATTN_BYTES);

  dim3 blk(256);
  hipLaunchKernelGGL(k_gemm0, dim3(2*624), blk, 0, stream,
                     (const void*)value, W_val, b_val, (void*)v);
  hipLaunchKernelGGL(k_gemm1, dim3(3*624), blk, 0, stream,
                     (const void*)query, W_off, W_attn, b_off, b_attn,
                     (void*)soff, sattn);
  hipLaunchKernelGGL(k_sample3, dim3(8*4*NCH), blk, 0, stream, v, soff, sattn, refp, tmp);
  hipLaunchKernelGGL(k_gemm2, dim3(2*624), blk, 0, stream,
                     (const void*)tmp, W_out, b_out, (void*)out);
}